// Round 4
// baseline (452.839 us; speedup 1.0000x reference)
//
#include <hip/hip_runtime.h>
#include <math.h>

// Problem constants: EMBED=256, HEADS=8, LEVELS=1, POINTS=4, QUEUE=2, 200x200
#define NQ    40000
#define EMB   256
#define NHEAD 8
#define HDIM  32
#define HB    200
#define WB    200
#define NCOL  192     // 128 off cols + 64 aw cols

typedef __attribute__((ext_vector_type(8))) __bf16 bf16x8;
typedef __attribute__((ext_vector_type(4))) float f32x4;

static __device__ __forceinline__ unsigned short f2bf(float f) {
  unsigned u = __float_as_uint(f);
  u = u + 0x7fffu + ((u >> 16) & 1u);   // round-to-nearest-even
  return (unsigned short)(u >> 16);
}
static __device__ __forceinline__ float bf2f(unsigned short s) {
  return __uint_as_float(((unsigned)s) << 16);
}

// ---------------------------------------------------------------------------
// conv_w: transposed bf16 weights + combined bias (tiny, one-shot)
// ---------------------------------------------------------------------------
__global__ __launch_bounds__(256) void conv_w(
    const float* __restrict__ W_off, const float* __restrict__ b_off,
    const float* __restrict__ W_attn, const float* __restrict__ b_attn,
    const float* __restrict__ W_val, const float* __restrict__ W_out,
    unsigned short* __restrict__ Wc1t, unsigned short* __restrict__ Wvt,
    unsigned short* __restrict__ Wot, float* __restrict__ bc1)
{
  int idx = blockIdx.x * 256 + threadIdx.x;
  if (idx < 98304) {                       // Wc1t [192][512]
    int n = idx >> 9, k = idx & 511;
    float v = (n < 128) ? W_off[(size_t)k * 128 + n] : W_attn[(size_t)k * 64 + (n - 128)];
    Wc1t[idx] = f2bf(v);
  } else if (idx < 163840) {               // Wvt [256][256]
    int j = idx - 98304;
    int n = j >> 8, k = j & 255;
    Wvt[j] = f2bf(W_val[(size_t)k * 256 + n]);
  } else if (idx < 229376) {               // Wot [256][256]
    int j = idx - 163840;
    int n = j >> 8, k = j & 255;
    Wot[j] = f2bf(W_out[(size_t)k * 256 + n]);
  } else if (idx < 229568) {               // bc1 [192]
    int n = idx - 229376;
    bc1[n] = (n < 128) ? b_off[n] : b_attn[n - 128];
  }
}

// ---------------------------------------------------------------------------
// MFMA bf16 GEMM, full-width N tile: C[M x N] = A[M x K] @ Bt[N x K]^T + bias
// BM=64, BN=N (grid.y=1: A read exactly once), BK=64.
// 4 waves (2x2): wave tile 32 x N/2 = 2 x (N/32) frags of 16x16x32.
// AMODE: 0 = A bf16 [M][K]; 1 = A fp32 (convert in staging);
//        2 = synth q2 (col<256: value fp32; else query+query_pos fp32).
// OMODE: 0 = fp32 direct store (+optional resid; 64B-line aligned segments);
//        1 = bf16 via LDS transpose -> uint4 stores (full lines, no RMW).
// M must be a multiple of 64 (all call sites: 40000/80000).
// ---------------------------------------------------------------------------
template<int K, int N, int AMODE, int OMODE, bool RESID>
__global__ __launch_bounds__(256) void mfma_gemm(
    const void* __restrict__ Aptr, const float* __restrict__ Aq,
    const float* __restrict__ Aqp, const unsigned short* __restrict__ Bt,
    const float* __restrict__ bias, const float* __restrict__ resid,
    void* __restrict__ outp)
{
  constexpr int NFR = N / 32;          // n-frags per wave
  constexpr int NBL = N / 32;          // B staging uint4s per thread
  __shared__ unsigned short As[64][80];
  __shared__ unsigned short Bs[N][80];
  const int t = threadIdx.x;
  const int m0 = blockIdx.x * 64;
  const int wid = t >> 6, lane = t & 63;
  const int wm = (wid >> 1) * 32, wn = (wid & 1) * (N / 2);
  const int lr = lane & 15, quad = lane >> 4;

  f32x4 acc[2][NFR];
  #pragma unroll
  for (int i = 0; i < 2; i++)
    #pragma unroll
    for (int n = 0; n < NFR; n++) acc[i][n] = (f32x4){0.f, 0.f, 0.f, 0.f};

  for (int k0 = 0; k0 < K; k0 += 64) {
    uint4 ra[2]; ushort4 ca[4];
    if constexpr (AMODE == 0) {
      const unsigned short* A = (const unsigned short*)Aptr;
      #pragma unroll
      for (int l = 0; l < 2; l++) {
        int e = t + l * 256, m = e >> 3, c8 = (e & 7) * 8;
        ra[l] = *(const uint4*)(A + (size_t)(m0 + m) * K + k0 + c8);
      }
    } else {
      const float* Av = (const float*)Aptr;
      #pragma unroll
      for (int l = 0; l < 4; l++) {
        int e = t + l * 256, m = e >> 4, c4 = (e & 15) * 4;
        int row = m0 + m;
        int kk = k0 + c4;
        float4 f;
        if constexpr (AMODE == 1) {
          f = *(const float4*)(Av + (size_t)row * K + kk);
        } else {
          if (kk < 256) {
            f = *(const float4*)(Av + (size_t)row * 256 + kk);
          } else {
            float4 x = *(const float4*)(Aq  + (size_t)row * 256 + (kk - 256));
            float4 y = *(const float4*)(Aqp + (size_t)row * 256 + (kk - 256));
            f = make_float4(x.x + y.x, x.y + y.y, x.z + y.z, x.w + y.w);
          }
        }
        ca[l].x = f2bf(f.x); ca[l].y = f2bf(f.y);
        ca[l].z = f2bf(f.z); ca[l].w = f2bf(f.w);
      }
    }
    uint4 rb[NBL];
    #pragma unroll
    for (int l = 0; l < NBL; l++) {
      int e = t + l * 256, n = e >> 3, c8 = (e & 7) * 8;
      rb[l] = *(const uint4*)(Bt + (size_t)n * K + k0 + c8);
    }
    __syncthreads();   // prior iteration's LDS reads complete
    if constexpr (AMODE == 0) {
      #pragma unroll
      for (int l = 0; l < 2; l++) {
        int e = t + l * 256, m = e >> 3, c8 = (e & 7) * 8;
        *(uint4*)(&As[m][c8]) = ra[l];
      }
    } else {
      #pragma unroll
      for (int l = 0; l < 4; l++) {
        int e = t + l * 256, m = e >> 4, c4 = (e & 15) * 4;
        *(ushort4*)(&As[m][c4]) = ca[l];
      }
    }
    #pragma unroll
    for (int l = 0; l < NBL; l++) {
      int e = t + l * 256, n = e >> 3, c8 = (e & 7) * 8;
      *(uint4*)(&Bs[n][c8]) = rb[l];
    }
    __syncthreads();
    #pragma unroll
    for (int kk = 0; kk < 64; kk += 32) {
      bf16x8 af[2], bfr[NFR];
      #pragma unroll
      for (int i = 0; i < 2; i++)
        af[i] = *(const bf16x8*)(&As[wm + i * 16 + lr][kk + quad * 8]);
      #pragma unroll
      for (int n = 0; n < NFR; n++)
        bfr[n] = *(const bf16x8*)(&Bs[wn + n * 16 + lr][kk + quad * 8]);
      #pragma unroll
      for (int i = 0; i < 2; i++)
        #pragma unroll
        for (int n = 0; n < NFR; n++)
          acc[i][n] = __builtin_amdgcn_mfma_f32_16x16x32_bf16(af[i], bfr[n], acc[i][n], 0, 0, 0);
    }
  }

  // epilogue: C/D layout col=lane&15, row=quad*4+reg
  if constexpr (OMODE == 0) {
    #pragma unroll
    for (int i = 0; i < 2; i++) {
      int rowb = m0 + wm + i * 16 + quad * 4;
      #pragma unroll
      for (int n = 0; n < NFR; n++) {
        int col = wn + n * 16 + lr;
        float bsv = bias[col];
        #pragma unroll
        for (int r = 0; r < 4; r++) {
          int rr = rowb + r;
          float v = acc[i][n][r] + bsv;
          if (RESID) v += resid[(size_t)rr * N + col];
          ((float*)outp)[(size_t)rr * N + col] = v;
        }
      }
    }
  } else {
    // bf16 out: transpose through LDS so stores are contiguous uint4
    __syncthreads();                     // main-loop LDS reads done
    unsigned short* trn = &Bs[0][0];     // 64 x (N+8) ushorts, fits in Bs
    constexpr int NP = N + 8;
    #pragma unroll
    for (int i = 0; i < 2; i++) {
      #pragma unroll
      for (int n = 0; n < NFR; n++) {
        int col = wn + n * 16 + lr;
        float bsv = bias[col];
        #pragma unroll
        for (int r = 0; r < 4; r++) {
          int rl = wm + i * 16 + quad * 4 + r;
          trn[rl * NP + col] = f2bf(acc[i][n][r] + bsv);
        }
      }
    }
    __syncthreads();
    constexpr int NCH = N / 32;          // uint4 chunks per thread
    #pragma unroll
    for (int l = 0; l < NCH; l++) {
      int c = t + l * 256;
      int row = c / (N / 8);
      int coloff = (c % (N / 8)) * 8;
      uint4 d = *(const uint4*)(trn + row * NP + coloff);
      *(uint4*)((unsigned short*)outp + (size_t)(m0 + row) * N + coloff) = d;
    }
  }
}

// ---------------------------------------------------------------------------
// K3: deformable sampling + queue mean. 2 queries/block. raw1 is bf16 now.
// Phase 1 (128 thr): per (s,b,h,p) -> 4 corner offsets + 4 combined weights.
// Phase 2 (256 thr): 4 uint gathers + 8 FMAs per sample.
// ---------------------------------------------------------------------------
__global__ __launch_bounds__(256) void k3_sample(
    const unsigned short* __restrict__ raw1, const float* __restrict__ refp,
    const unsigned short* __restrict__ v, unsigned short* __restrict__ msd)
{
  __shared__ int4   sidx[2][64];
  __shared__ float4 swgt[2][64];
  const int t = threadIdx.x;
  const int q0 = blockIdx.x * 2;

  if (t < 128) {
    const int s = t >> 6, e = t & 63;
    const int b = e >> 5, h = (e >> 2) & 7, p = e & 3;
    const int q = q0 + s;
    const unsigned short* r = raw1 + (size_t)q * NCOL;
    float ox = bf2f(r[h * 16 + b * 8 + p * 2 + 0]);
    float oy = bf2f(r[h * 16 + b * 8 + p * 2 + 1]);
    float l0 = bf2f(r[128 + h * 8 + b * 4 + 0]);
    float l1 = bf2f(r[128 + h * 8 + b * 4 + 1]);
    float l2 = bf2f(r[128 + h * 8 + b * 4 + 2]);
    float l3 = bf2f(r[128 + h * 8 + b * 4 + 3]);
    float mx = fmaxf(fmaxf(l0, l1), fmaxf(l2, l3));
    float e0 = expf(l0 - mx), e1 = expf(l1 - mx);
    float e2 = expf(l2 - mx), e3 = expf(l3 - mx);
    float ssum = e0 + e1 + e2 + e3;
    float ep = (p == 0) ? e0 : (p == 1) ? e1 : (p == 2) ? e2 : e3;
    float aw = ep / ssum * 0.5f;          // fold queue-mean 0.5 here
    float rx = refp[((size_t)b * NQ + q) * 2 + 0];
    float ry = refp[((size_t)b * NQ + q) * 2 + 1];
    float px = rx * (float)WB + ox - 0.5f;
    float py = ry * (float)HB + oy - 0.5f;
    float x0f = floorf(px), y0f = floorf(py);
    float lx = px - x0f, ly = py - y0f;
    int x0 = (int)x0f, y0 = (int)y0f, x1 = x0 + 1, y1 = y0 + 1;
    int x0c = min(max(x0, 0), WB - 1), x1c = min(max(x1, 0), WB - 1);
    int y0c = min(max(y0, 0), HB - 1), y1c = min(max(y1, 0), HB - 1);
    float vx0 = ((unsigned)x0 < (unsigned)WB) ? 1.f : 0.f;
    float vx1 = ((unsigned)x1 < (unsigned)WB) ? 1.f : 0.f;
    float vy0 = ((unsigned)y0 < (unsigned)HB) ? 1.f : 0.f;
    float vy1 = ((unsigned)y1 < (unsigned)HB) ? 1.f : 0.f;
    const int pb = b * NQ;
    const int hb = h * HDIM;
    int4 ix;
    ix.x = (pb + y0c * WB + x0c) * EMB + hb;
    ix.y = (pb + y0c * WB + x1c) * EMB + hb;
    ix.z = (pb + y1c * WB + x0c) * EMB + hb;
    ix.w = (pb + y1c * WB + x1c) * EMB + hb;
    float4 wv;
    wv.x = aw * (1.f - lx) * (1.f - ly) * vx0 * vy0;
    wv.y = aw * lx * (1.f - ly) * vx1 * vy0;
    wv.z = aw * (1.f - lx) * ly * vx0 * vy1;
    wv.w = aw * lx * ly * vx1 * vy1;
    sidx[s][e] = ix;
    swgt[s][e] = wv;
  }
  __syncthreads();

  const int s = t >> 7, u = t & 127;
  const int h = u >> 4, d2 = u & 15;
  const unsigned short* vd = v + d2 * 2;
  float a0 = 0.f, a1 = 0.f;
  #pragma unroll
  for (int b = 0; b < 2; b++) {
    #pragma unroll
    for (int p = 0; p < 4; p++) {
      int ent = b * 32 + h * 4 + p;
      int4 ix = sidx[s][ent];
      float4 wv = swgt[s][ent];
      unsigned c00 = *(const unsigned*)(vd + ix.x);
      unsigned c10 = *(const unsigned*)(vd + ix.y);
      unsigned c01 = *(const unsigned*)(vd + ix.z);
      unsigned c11 = *(const unsigned*)(vd + ix.w);
      a0 += wv.x * __uint_as_float(c00 << 16);
      a1 += wv.x * __uint_as_float(c00 & 0xffff0000u);
      a0 += wv.y * __uint_as_float(c10 << 16);
      a1 += wv.y * __uint_as_float(c10 & 0xffff0000u);
      a0 += wv.z * __uint_as_float(c01 << 16);
      a1 += wv.z * __uint_as_float(c01 & 0xffff0000u);
      a0 += wv.w * __uint_as_float(c11 << 16);
      a1 += wv.w * __uint_as_float(c11 & 0xffff0000u);
    }
  }
  unsigned pack = ((unsigned)f2bf(a1) << 16) | (unsigned)f2bf(a0);
  *(unsigned*)(msd + (size_t)(q0 + s) * EMB + h * HDIM + d2 * 2) = pack;
}

// ---------------------------------------------------------------------------
extern "C" void kernel_launch(void* const* d_in, const int* in_sizes, int n_in,
                              void* d_out, int out_size, void* d_ws, size_t ws_size,
                              hipStream_t stream) {
  const float* query     = (const float*)d_in[0];
  const float* query_pos = (const float*)d_in[1];
  const float* value     = (const float*)d_in[2];
  const float* refp      = (const float*)d_in[3];
  // d_in[4]: spatial_shapes constant [200,200]
  const float* W_off  = (const float*)d_in[5];
  const float* b_off  = (const float*)d_in[6];
  const float* W_attn = (const float*)d_in[7];
  const float* b_attn = (const float*)d_in[8];
  const float* W_val  = (const float*)d_in[9];
  const float* b_val  = (const float*)d_in[10];
  const float* W_out  = (const float*)d_in[11];
  const float* b_out  = (const float*)d_in[12];
  float* out = (float*)d_out;

  char* ws = (char*)d_ws;
  unsigned short* raw1 = (unsigned short*)(ws);            // 40000*192*2 = 15,360,000
  unsigned short* vout = (unsigned short*)(ws + 15360000); // 80000*256*2 = 40,960,000
  unsigned short* msdb = (unsigned short*)(ws + 56320000); // 40000*256*2 = 20,480,000
  unsigned short* Wc1t = (unsigned short*)(ws + 76800000); // 192*512*2  =    196,608
  unsigned short* Wvt  = (unsigned short*)(ws + 76996608); // 256*256*2  =    131,072
  unsigned short* Wot  = (unsigned short*)(ws + 77127680); // 256*256*2  =    131,072
  float*          bc1  = (float*)(ws + 77258752);          // 192*4

  hipLaunchKernelGGL(conv_w, dim3(897), dim3(256), 0, stream,
                     W_off, b_off, W_attn, b_attn, W_val, W_out, Wc1t, Wvt, Wot, bc1);

  // k1: raw1 = q2 @ [W_off|W_attn] + bc1  (40000x512 @ 512x192), synth A, bf16 out
  hipLaunchKernelGGL((mfma_gemm<512, 192, 2, 1, false>),
                     dim3(625), dim3(256), 0, stream,
                     (const void*)value, query, query_pos, Wc1t, bc1,
                     (const float*)nullptr, (void*)raw1);
  // k2: v = value @ W_val + b_val  (80000x256 @ 256x256), fp32 A convert, bf16 out
  hipLaunchKernelGGL((mfma_gemm<256, 256, 1, 1, false>),
                     dim3(1250), dim3(256), 0, stream,
                     (const void*)value, (const float*)nullptr, (const float*)nullptr,
                     Wvt, b_val, (const float*)nullptr, (void*)vout);
  // k3: sampling + queue mean -> msd bf16
  hipLaunchKernelGGL(k3_sample, dim3(NQ / 2), dim3(256), 0, stream,
                     raw1, refp, vout, msdb);
  // k4: out = msd @ W_out + b_out + query  (40000x256 @ 256x256), fp32 out + resid
  hipLaunchKernelGGL((mfma_gemm<256, 256, 0, 0, true>),
                     dim3(625), dim3(256), 0, stream,
                     (const void*)msdb, (const float*)nullptr, (const float*)nullptr,
                     Wot, b_out, query, (void*)out);
}

// Round 5
// 392.977 us; speedup vs baseline: 1.1523x; 1.1523x over previous
//
#include <hip/hip_runtime.h>
#include <math.h>

// Problem constants: EMBED=256, HEADS=8, LEVELS=1, POINTS=4, QUEUE=2, 200x200
#define NQ    40000
#define EMB   256
#define NHEAD 8
#define HDIM  32
#define HB    200
#define WB    200
#define NCOL  192     // 128 off cols + 64 aw cols

typedef __attribute__((ext_vector_type(8))) __bf16 bf16x8;
typedef __attribute__((ext_vector_type(4))) float f32x4;

static __device__ __forceinline__ unsigned short f2bf(float f) {
  unsigned u = __float_as_uint(f);
  u = u + 0x7fffu + ((u >> 16) & 1u);   // round-to-nearest-even
  return (unsigned short)(u >> 16);
}
static __device__ __forceinline__ float bf2f(unsigned short s) {
  return __uint_as_float(((unsigned)s) << 16);
}

// ---------------------------------------------------------------------------
// conv_w: transposed bf16 weights + combined bias (tiny, one-shot)
// ---------------------------------------------------------------------------
__global__ __launch_bounds__(256) void conv_w(
    const float* __restrict__ W_off, const float* __restrict__ b_off,
    const float* __restrict__ W_attn, const float* __restrict__ b_attn,
    const float* __restrict__ W_val, const float* __restrict__ W_out,
    unsigned short* __restrict__ Wc1t, unsigned short* __restrict__ Wvt,
    unsigned short* __restrict__ Wot, float* __restrict__ bc1)
{
  int idx = blockIdx.x * 256 + threadIdx.x;
  if (idx < 98304) {                       // Wc1t [192][512]
    int n = idx >> 9, k = idx & 511;
    float v = (n < 128) ? W_off[(size_t)k * 128 + n] : W_attn[(size_t)k * 64 + (n - 128)];
    Wc1t[idx] = f2bf(v);
  } else if (idx < 163840) {               // Wvt [256][256]
    int j = idx - 98304;
    int n = j >> 8, k = j & 255;
    Wvt[j] = f2bf(W_val[(size_t)k * 256 + n]);
  } else if (idx < 229376) {               // Wot [256][256]
    int j = idx - 163840;
    int n = j >> 8, k = j & 255;
    Wot[j] = f2bf(W_out[(size_t)k * 256 + n]);
  } else if (idx < 229568) {               // bc1 [192]
    int n = idx - 229376;
    bc1[n] = (n < 128) ? b_off[n] : b_attn[n - 128];
  }
}

// ---------------------------------------------------------------------------
// Barrier-free register GEMM: C[M x N] = A[M x K] @ Bt[N x K]^T + bias.
// NO LDS in the K-loop: B frags stream from global (L2-hot, <=196 KB working
// set), A frags load directly in MFMA A-layout (lane lr = row, quad = k/8;
// per row the 4 quads cover 128 contiguous bytes fp32 / 64 B bf16).
// Block = 256 thr = 4 waves (2m x 2n); wave tile 32 x N/2; BM = 64.
// AMODE: 0 = A bf16 [M][K]; 1 = A fp32; 2 = synth q2 (value | query+qpos).
// OMODE: 0 = fp32 direct store (+resid); 1 = bf16 via LDS transpose.
// ---------------------------------------------------------------------------
template<int K, int N, int AMODE, int OMODE, bool RESID>
__global__ __launch_bounds__(256) void rb_gemm(
    const void* __restrict__ Aptr, const float* __restrict__ Aq,
    const float* __restrict__ Aqp, const unsigned short* __restrict__ Bt,
    const float* __restrict__ bias, const float* __restrict__ resid,
    void* __restrict__ outp)
{
  constexpr int NFR = N / 32;              // 16-col n-frags per wave
  constexpr int NP  = N + 8;
  constexpr int TRN = (OMODE == 1) ? 64 * NP : 64;
  __shared__ unsigned short trn[TRN];

  const int t = threadIdx.x;
  const int m0 = blockIdx.x * 64;
  const int wid = t >> 6, lane = t & 63;
  const int wm = (wid >> 1) * 32, wn = (wid & 1) * (N / 2);
  const int lr = lane & 15, quad = lane >> 4;
  const int arow0 = m0 + wm + lr;

  f32x4 acc[2][NFR];
  #pragma unroll
  for (int i = 0; i < 2; i++)
    #pragma unroll
    for (int n = 0; n < NFR; n++) acc[i][n] = (f32x4){0.f, 0.f, 0.f, 0.f};

  #pragma unroll 2
  for (int k0 = 0; k0 < K; k0 += 32) {
    const int kf = k0 + quad * 8;
    bf16x8 bfr[NFR];
    #pragma unroll
    for (int n = 0; n < NFR; n++)
      bfr[n] = *(const bf16x8*)(Bt + (size_t)(wn + n * 16 + lr) * K + kf);

    bf16x8 af[2];
    if constexpr (AMODE == 0) {
      const unsigned short* A = (const unsigned short*)Aptr;
      #pragma unroll
      for (int i = 0; i < 2; i++)
        af[i] = *(const bf16x8*)(A + (size_t)(arow0 + i * 16) * K + kf);
    } else {
      #pragma unroll
      for (int i = 0; i < 2; i++) {
        const int row = arow0 + i * 16;
        float4 f0, f1;
        if constexpr (AMODE == 1) {
          const float* Av = (const float*)Aptr;
          f0 = *(const float4*)(Av + (size_t)row * K + kf);
          f1 = *(const float4*)(Av + (size_t)row * K + kf + 4);
        } else {
          if (k0 < 256) {
            const float* Av = (const float*)Aptr;
            f0 = *(const float4*)(Av + (size_t)row * 256 + kf);
            f1 = *(const float4*)(Av + (size_t)row * 256 + kf + 4);
          } else {
            const int kq = kf - 256;
            float4 x0 = *(const float4*)(Aq  + (size_t)row * 256 + kq);
            float4 y0 = *(const float4*)(Aqp + (size_t)row * 256 + kq);
            float4 x1 = *(const float4*)(Aq  + (size_t)row * 256 + kq + 4);
            float4 y1 = *(const float4*)(Aqp + (size_t)row * 256 + kq + 4);
            f0 = make_float4(x0.x + y0.x, x0.y + y0.y, x0.z + y0.z, x0.w + y0.w);
            f1 = make_float4(x1.x + y1.x, x1.y + y1.y, x1.z + y1.z, x1.w + y1.w);
          }
        }
        union { unsigned short us[8]; bf16x8 v; } u;
        u.us[0] = f2bf(f0.x); u.us[1] = f2bf(f0.y);
        u.us[2] = f2bf(f0.z); u.us[3] = f2bf(f0.w);
        u.us[4] = f2bf(f1.x); u.us[5] = f2bf(f1.y);
        u.us[6] = f2bf(f1.z); u.us[7] = f2bf(f1.w);
        af[i] = u.v;
      }
    }
    #pragma unroll
    for (int i = 0; i < 2; i++)
      #pragma unroll
      for (int n = 0; n < NFR; n++)
        acc[i][n] = __builtin_amdgcn_mfma_f32_16x16x32_bf16(af[i], bfr[n], acc[i][n], 0, 0, 0);
  }

  // epilogue: C/D layout col=lane&15, row=quad*4+reg
  if constexpr (OMODE == 0) {
    #pragma unroll
    for (int i = 0; i < 2; i++) {
      int rowb = m0 + wm + i * 16 + quad * 4;
      #pragma unroll
      for (int n = 0; n < NFR; n++) {
        int col = wn + n * 16 + lr;
        float bsv = bias[col];
        #pragma unroll
        for (int r = 0; r < 4; r++) {
          int rr = rowb + r;
          float v = acc[i][n][r] + bsv;
          if (RESID) v += resid[(size_t)rr * N + col];
          ((float*)outp)[(size_t)rr * N + col] = v;
        }
      }
    }
  } else {
    // bf16 out via LDS transpose -> full-line uint4 stores
    #pragma unroll
    for (int i = 0; i < 2; i++) {
      #pragma unroll
      for (int n = 0; n < NFR; n++) {
        int col = wn + n * 16 + lr;
        float bsv = bias[col];
        #pragma unroll
        for (int r = 0; r < 4; r++) {
          int rl = wm + i * 16 + quad * 4 + r;
          trn[rl * NP + col] = f2bf(acc[i][n][r] + bsv);
        }
      }
    }
    __syncthreads();
    constexpr int NCH = N / 32;          // uint4 chunks per thread
    #pragma unroll
    for (int l = 0; l < NCH; l++) {
      int c = t + l * 256;
      int row = c / (N / 8);
      int coloff = (c % (N / 8)) * 8;
      uint4 d = *(const uint4*)(trn + row * NP + coloff);
      *(uint4*)((unsigned short*)outp + (size_t)(m0 + row) * N + coloff) = d;
    }
  }
}

// ---------------------------------------------------------------------------
// K3: deformable sampling + queue mean. 2 queries/block. raw1 bf16.
// ---------------------------------------------------------------------------
__global__ __launch_bounds__(256) void k3_sample(
    const unsigned short* __restrict__ raw1, const float* __restrict__ refp,
    const unsigned short* __restrict__ v, unsigned short* __restrict__ msd)
{
  __shared__ int4   sidx[2][64];
  __shared__ float4 swgt[2][64];
  const int t = threadIdx.x;
  const int q0 = blockIdx.x * 2;

  if (t < 128) {
    const int s = t >> 6, e = t & 63;
    const int b = e >> 5, h = (e >> 2) & 7, p = e & 3;
    const int q = q0 + s;
    const unsigned short* r = raw1 + (size_t)q * NCOL;
    float ox = bf2f(r[h * 16 + b * 8 + p * 2 + 0]);
    float oy = bf2f(r[h * 16 + b * 8 + p * 2 + 1]);
    float l0 = bf2f(r[128 + h * 8 + b * 4 + 0]);
    float l1 = bf2f(r[128 + h * 8 + b * 4 + 1]);
    float l2 = bf2f(r[128 + h * 8 + b * 4 + 2]);
    float l3 = bf2f(r[128 + h * 8 + b * 4 + 3]);
    float mx = fmaxf(fmaxf(l0, l1), fmaxf(l2, l3));
    float e0 = expf(l0 - mx), e1 = expf(l1 - mx);
    float e2 = expf(l2 - mx), e3 = expf(l3 - mx);
    float ssum = e0 + e1 + e2 + e3;
    float ep = (p == 0) ? e0 : (p == 1) ? e1 : (p == 2) ? e2 : e3;
    float aw = ep / ssum * 0.5f;          // fold queue-mean 0.5
    float rx = refp[((size_t)b * NQ + q) * 2 + 0];
    float ry = refp[((size_t)b * NQ + q) * 2 + 1];
    float px = rx * (float)WB + ox - 0.5f;
    float py = ry * (float)HB + oy - 0.5f;
    float x0f = floorf(px), y0f = floorf(py);
    float lx = px - x0f, ly = py - y0f;
    int x0 = (int)x0f, y0 = (int)y0f, x1 = x0 + 1, y1 = y0 + 1;
    int x0c = min(max(x0, 0), WB - 1), x1c = min(max(x1, 0), WB - 1);
    int y0c = min(max(y0, 0), HB - 1), y1c = min(max(y1, 0), HB - 1);
    float vx0 = ((unsigned)x0 < (unsigned)WB) ? 1.f : 0.f;
    float vx1 = ((unsigned)x1 < (unsigned)WB) ? 1.f : 0.f;
    float vy0 = ((unsigned)y0 < (unsigned)HB) ? 1.f : 0.f;
    float vy1 = ((unsigned)y1 < (unsigned)HB) ? 1.f : 0.f;
    const int pb = b * NQ;
    const int hb = h * HDIM;
    int4 ix;
    ix.x = (pb + y0c * WB + x0c) * EMB + hb;
    ix.y = (pb + y0c * WB + x1c) * EMB + hb;
    ix.z = (pb + y1c * WB + x0c) * EMB + hb;
    ix.w = (pb + y1c * WB + x1c) * EMB + hb;
    float4 wv;
    wv.x = aw * (1.f - lx) * (1.f - ly) * vx0 * vy0;
    wv.y = aw * lx * (1.f - ly) * vx1 * vy0;
    wv.z = aw * (1.f - lx) * ly * vx0 * vy1;
    wv.w = aw * lx * ly * vx1 * vy1;
    sidx[s][e] = ix;
    swgt[s][e] = wv;
  }
  __syncthreads();

  const int s = t >> 7, u = t & 127;
  const int h = u >> 4, d2 = u & 15;
  const unsigned short* vd = v + d2 * 2;
  float a0 = 0.f, a1 = 0.f;
  #pragma unroll
  for (int b = 0; b < 2; b++) {
    #pragma unroll
    for (int p = 0; p < 4; p++) {
      int ent = b * 32 + h * 4 + p;
      int4 ix = sidx[s][ent];
      float4 wv = swgt[s][ent];
      unsigned c00 = *(const unsigned*)(vd + ix.x);
      unsigned c10 = *(const unsigned*)(vd + ix.y);
      unsigned c01 = *(const unsigned*)(vd + ix.z);
      unsigned c11 = *(const unsigned*)(vd + ix.w);
      a0 += wv.x * __uint_as_float(c00 << 16);
      a1 += wv.x * __uint_as_float(c00 & 0xffff0000u);
      a0 += wv.y * __uint_as_float(c10 << 16);
      a1 += wv.y * __uint_as_float(c10 & 0xffff0000u);
      a0 += wv.z * __uint_as_float(c01 << 16);
      a1 += wv.z * __uint_as_float(c01 & 0xffff0000u);
      a0 += wv.w * __uint_as_float(c11 << 16);
      a1 += wv.w * __uint_as_float(c11 & 0xffff0000u);
    }
  }
  unsigned pack = ((unsigned)f2bf(a1) << 16) | (unsigned)f2bf(a0);
  *(unsigned*)(msd + (size_t)(q0 + s) * EMB + h * HDIM + d2 * 2) = pack;
}

// ---------------------------------------------------------------------------
extern "C" void kernel_launch(void* const* d_in, const int* in_sizes, int n_in,
                              void* d_out, int out_size, void* d_ws, size_t ws_size,
                              hipStream_t stream) {
  const float* query     = (const float*)d_in[0];
  const float* query_pos = (const float*)d_in[1];
  const float* value     = (const float*)d_in[2];
  const float* refp      = (const float*)d_in[3];
  // d_in[4]: spatial_shapes constant [200,200]
  const float* W_off  = (const float*)d_in[5];
  const float* b_off  = (const float*)d_in[6];
  const float* W_attn = (const float*)d_in[7];
  const float* b_attn = (const float*)d_in[8];
  const float* W_val  = (const float*)d_in[9];
  const float* b_val  = (const float*)d_in[10];
  const float* W_out  = (const float*)d_in[11];
  const float* b_out  = (const float*)d_in[12];
  float* out = (float*)d_out;

  char* ws = (char*)d_ws;
  unsigned short* raw1 = (unsigned short*)(ws);            // 40000*192*2 = 15,360,000
  unsigned short* vout = (unsigned short*)(ws + 15360000); // 80000*256*2 = 40,960,000
  unsigned short* msdb = (unsigned short*)(ws + 56320000); // 40000*256*2 = 20,480,000
  unsigned short* Wc1t = (unsigned short*)(ws + 76800000); // 192*512*2
  unsigned short* Wvt  = (unsigned short*)(ws + 76996608); // 256*256*2
  unsigned short* Wot  = (unsigned short*)(ws + 77127680); // 256*256*2
  float*          bc1  = (float*)(ws + 77258752);          // 192*4

  hipLaunchKernelGGL(conv_w, dim3(897), dim3(256), 0, stream,
                     W_off, b_off, W_attn, b_attn, W_val, W_out, Wc1t, Wvt, Wot, bc1);

  // k1: raw1 = q2 @ [W_off|W_attn] + bc1  (40000x512 @ 512x192), synth A, bf16 out
  hipLaunchKernelGGL((rb_gemm<512, 192, 2, 1, false>),
                     dim3(625), dim3(256), 0, stream,
                     (const void*)value, query, query_pos, Wc1t, bc1,
                     (const float*)nullptr, (void*)raw1);
  // k2: v = value @ W_val + b_val  (80000x256 @ 256x256), fp32 A, bf16 out
  hipLaunchKernelGGL((rb_gemm<256, 256, 1, 1, false>),
                     dim3(1250), dim3(256), 0, stream,
                     (const void*)value, (const float*)nullptr, (const float*)nullptr,
                     Wvt, b_val, (const float*)nullptr, (void*)vout);
  // k3: sampling + queue mean -> msd bf16
  hipLaunchKernelGGL(k3_sample, dim3(NQ / 2), dim3(256), 0, stream,
                     raw1, refp, vout, msdb);
  // k4: out = msd @ W_out + b_out + query  (40000x256 @ 256x256), fp32 out + resid
  hipLaunchKernelGGL((rb_gemm<256, 256, 0, 0, true>),
                     dim3(625), dim3(256), 0, stream,
                     (const void*)msdb, (const float*)nullptr, (const float*)nullptr,
                     Wot, b_out, query, (void*)out);
}